// Round 1
// baseline (538.208 us; speedup 1.0000x reference)
//
#include <hip/hip_runtime.h>
#include <hip/hip_bf16.h>

// Problem constants (B,S,HID)=(4,8192,1024), H=16, D=64, CHUNK=64, N_BEFORE=1
#define NB 4
#define NS 8192
#define NHID 1024
#define NH 16
#define ND 64
#define NCHUNK 128  // S / 64

typedef __attribute__((ext_vector_type(8))) __bf16 bf16x8;
typedef __attribute__((ext_vector_type(4))) float f32x4;

__device__ __forceinline__ unsigned short f2bf(float x) {
  unsigned int u = __builtin_bit_cast(unsigned int, x);
  unsigned int r = (u + 0x7FFFu + ((u >> 16) & 1u)) >> 16;
  return (unsigned short)r;
}

__device__ __forceinline__ void gload16(const void* g, void* l) {
  __builtin_amdgcn_global_load_lds(
      (const __attribute__((address_space(1))) unsigned int*)g,
      (__attribute__((address_space(3))) unsigned int*)l, 16, 0, 0);
}

// ---------------- X fp32 -> bf16 ----------------
__global__ __launch_bounds__(256) void convert_x(const float* __restrict__ x,
                                                 unsigned short* __restrict__ xb) {
  int gt = blockIdx.x * 256 + threadIdx.x;
  const float4* xf = (const float4*)x;
  float4 v0 = xf[gt * 2 + 0];
  float4 v1 = xf[gt * 2 + 1];
  uint4 o;
  o.x = f2bf(v0.x) | ((unsigned)f2bf(v0.y) << 16);
  o.y = f2bf(v0.z) | ((unsigned)f2bf(v0.w) << 16);
  o.z = f2bf(v1.x) | ((unsigned)f2bf(v1.y) << 16);
  o.w = f2bf(v1.z) | ((unsigned)f2bf(v1.w) << 16);
  ((uint4*)xb)[gt] = o;
}

// ---------------- W [k][n] fp32 -> Wt [3][n][k] bf16 (K scaled by 1/8) -------
__global__ __launch_bounds__(256) void transpose_w(const float* __restrict__ w0,
                                                   const float* __restrict__ w1,
                                                   const float* __restrict__ w2,
                                                   unsigned short* __restrict__ wt) {
  __shared__ float tile[32][33];
  int wi = blockIdx.z;
  const float* w = (wi == 0) ? w0 : ((wi == 1) ? w1 : w2);
  float scale = (wi == 1) ? 0.125f : 1.0f;  // 1/sqrt(D) folded into Wk
  int k0 = blockIdx.x * 32, n0 = blockIdx.y * 32;
  int tx = threadIdx.x, ty = threadIdx.y;  // 32 x 8
#pragma unroll
  for (int i = 0; i < 4; i++)
    tile[ty + i * 8][tx] = w[(k0 + ty + i * 8) * NHID + n0 + tx];
  __syncthreads();
#pragma unroll
  for (int i = 0; i < 4; i++)
    wt[(wi * NHID + n0 + ty + i * 8) * NHID + k0 + tx] =
        f2bf(tile[tx][ty + i * 8] * scale);
}

// ---------------- QKV GEMM: X[32768,1024] @ Wt^T -> Q/K/V [b][h][s][d] bf16 --
// m97 structure: 128x128 tile, BK=32, 4 waves (2x2), global_load_lds(16B).
__global__ __launch_bounds__(256, 2) void gemm_qkv(
    const unsigned short* __restrict__ xb, const unsigned short* __restrict__ wt,
    unsigned short* __restrict__ qg, unsigned short* __restrict__ kg,
    unsigned short* __restrict__ vg) {
  __shared__ alignas(16) unsigned short As[128 * 32];
  __shared__ alignas(16) unsigned short Bs[128 * 32];
  int bn = blockIdx.x, bm = blockIdx.y;  // bn fast: A-tile reused across bn in L2
  int t = threadIdx.x;
  int w = t >> 6, l = t & 63, lg = l >> 4, lm = l & 15;
  int wr = w >> 1, wc = w & 1;
  f32x4 acc[4][4] = {};

  for (int kt = 0; kt < NHID / 32; ++kt) {
    int k0 = kt * 32;
    __syncthreads();
#pragma unroll
    for (int i = 0; i < 2; i++) {
      int g = t + i * 256;            // 512 granules of 16B per 8KB tile
      int row = g >> 2, cc = g & 3;   // 4 granules per 32-elem row
      gload16(xb + (size_t)(bm * 128 + row) * NHID + k0 + cc * 8,
              (char*)As + g * 16);
      gload16(wt + (size_t)(bn * 128 + row) * NHID + k0 + cc * 8,
              (char*)Bs + g * 16);
    }
    __syncthreads();
    bf16x8 av[4], bv[4];
#pragma unroll
    for (int mi = 0; mi < 4; mi++) {
      int row = wr * 64 + mi * 16 + lm;
      av[mi] = *reinterpret_cast<const bf16x8*>(&As[row * 32 + lg * 8]);
    }
#pragma unroll
    for (int ni = 0; ni < 4; ni++) {
      int row = wc * 64 + ni * 16 + lm;
      bv[ni] = *reinterpret_cast<const bf16x8*>(&Bs[row * 32 + lg * 8]);
    }
#pragma unroll
    for (int mi = 0; mi < 4; mi++)
#pragma unroll
      for (int ni = 0; ni < 4; ni++)
        acc[mi][ni] = __builtin_amdgcn_mfma_f32_16x16x32_bf16(
            av[mi], bv[ni], acc[mi][ni], 0, 0, 0);
  }

  // Epilogue: scatter to [b][h][s][d] bf16. Whole tile is one weight (1024/128=8).
  int gn0 = bn * 128;
  int wsel = gn0 >> 10;
  unsigned short* dst = (wsel == 0) ? qg : ((wsel == 1) ? kg : vg);
#pragma unroll
  for (int mi = 0; mi < 4; mi++)
#pragma unroll
    for (int ni = 0; ni < 4; ni++)
#pragma unroll
      for (int r = 0; r < 4; r++) {
        int gm = bm * 128 + wr * 64 + mi * 16 + lg * 4 + r;  // row = m
        int gn = gn0 + wc * 64 + ni * 16 + lm;               // col = n
        int b = gm >> 13, s = gm & (NS - 1);
        int h = (gn >> 6) & (NH - 1), d = gn & (ND - 1);
        dst[(((size_t)(b * NH + h) * NS) + s) * ND + d] = f2bf(acc[mi][ni][r]);
      }
}

// ---------------- Local attention: block = (chunk c, head h, batch b) --------
// 4 waves x 16 q-rows. S=Q K^T (16x16x32 MFMA), in-wave softmax, P via LDS, PV.
__global__ __launch_bounds__(256, 2) void attn_local(
    const unsigned short* __restrict__ qg, const unsigned short* __restrict__ kg,
    const unsigned short* __restrict__ vg, float* __restrict__ out) {
  __shared__ alignas(16) unsigned short qs[64 * 64];    // 8KB  [q][d]
  __shared__ alignas(16) unsigned short ks2[128 * 64];  // 16KB [kv][d]
  __shared__ alignas(16) unsigned short vts[64 * 128];  // 16KB [d][kv] (V^T)
  __shared__ alignas(16) unsigned short ps[64 * 128];   // 16KB [q][kv]
  int c = blockIdx.x, h = blockIdx.y, b = blockIdx.z;
  int t = threadIdx.x;
  int w = t >> 6, l = t & 63, lg = l >> 4, lm = l & 15;
  size_t bhbase = (size_t)(b * NH + h) * NS * ND;
  int kv0 = (c - 1) * 64;  // global s of kv col 0 (negative for c==0: masked)

  // stage Q [64][64], XOR-swizzled rows (stride 128B)
#pragma unroll
  for (int i = 0; i < 2; i++) {
    int g = t + i * 256;
    int row = g >> 3, cc = g & 7;
    uint4 v = *reinterpret_cast<const uint4*>(qg + bhbase +
                                              (size_t)(c * 64 + row) * ND + cc * 8);
    int byte = (row * 128 + cc * 16) ^ ((row & 7) << 4);
    *reinterpret_cast<uint4*>((char*)qs + byte) = v;
  }
  // stage K [128][64]
#pragma unroll
  for (int i = 0; i < 4; i++) {
    int g = t + i * 256;
    int row = g >> 3, cc = g & 7;
    int s = kv0 + row;
    if (s < 0) s = 0;  // garbage rows fully masked later
    uint4 v = *reinterpret_cast<const uint4*>(kg + bhbase + (size_t)s * ND + cc * 8);
    int byte = (row * 128 + cc * 16) ^ ((row & 7) << 4);
    *reinterpret_cast<uint4*>((char*)ks2 + byte) = v;
  }
  // stage V transposed -> vts[d][kv], b16 scatter, col ^= (d&7)<<3
  {
    int k = t >> 1, half = t & 1;
    int s = kv0 + k;
    if (s < 0) s = 0;
#pragma unroll
    for (int i = 0; i < 4; i++) {
      int d0 = half * 32 + i * 8;
      uint4 v = *reinterpret_cast<const uint4*>(vg + bhbase + (size_t)s * ND + d0);
      unsigned int u[4] = {v.x, v.y, v.z, v.w};
#pragma unroll
      for (int j = 0; j < 8; j++) {
        unsigned short val = (unsigned short)(u[j >> 1] >> ((j & 1) * 16));
        vts[(d0 + j) * 128 + (k ^ (j << 3))] = val;  // (d0+j)&7 == j
      }
    }
  }
  __syncthreads();

  // ---- S = Q K^T : wave w owns q rows [w*16, w*16+16), all 128 kv cols ----
  bf16x8 qa[2];
#pragma unroll
  for (int ks = 0; ks < 2; ks++) {
    int row = w * 16 + lm;
    int byte = (row * 128 + (ks * 32 + lg * 8) * 2) ^ ((row & 7) << 4);
    qa[ks] = *reinterpret_cast<const bf16x8*>((char*)qs + byte);
  }
  f32x4 sf[8];
#pragma unroll
  for (int nt = 0; nt < 8; nt++) {
    f32x4 a = {};
#pragma unroll
    for (int ks = 0; ks < 2; ks++) {
      int n = nt * 16 + lm;
      int byte = (n * 128 + (ks * 32 + lg * 8) * 2) ^ ((n & 7) << 4);
      bf16x8 kb = *reinterpret_cast<const bf16x8*>((char*)ks2 + byte);
      a = __builtin_amdgcn_mfma_f32_16x16x32_bf16(qa[ks], kb, a, 0, 0, 0);
    }
    sf[nt] = a;  // S[q = w*16+lg*4+r][kv = nt*16+lm]
  }

  // ---- masked softmax, rows stay in 16-lane groups ----
  float mx[4] = {-1e30f, -1e30f, -1e30f, -1e30f};
#pragma unroll
  for (int nt = 0; nt < 8; nt++) {
    int j = nt * 16 + lm;
#pragma unroll
    for (int r = 0; r < 4; r++) {
      int q = w * 16 + lg * 4 + r;
      bool valid = (j <= q + 64) && (c > 0 || j >= 64);
      if (valid) mx[r] = fmaxf(mx[r], sf[nt][r]);
    }
  }
#pragma unroll
  for (int r = 0; r < 4; r++)
#pragma unroll
    for (int d = 1; d < 16; d <<= 1) mx[r] = fmaxf(mx[r], __shfl_xor(mx[r], d, 64));

  float sum[4] = {0.f, 0.f, 0.f, 0.f};
#pragma unroll
  for (int nt = 0; nt < 8; nt++) {
    int j = nt * 16 + lm;
#pragma unroll
    for (int r = 0; r < 4; r++) {
      int q = w * 16 + lg * 4 + r;
      bool valid = (j <= q + 64) && (c > 0 || j >= 64);
      float p = valid ? __expf(sf[nt][r] - mx[r]) : 0.0f;
      sf[nt][r] = p;
      sum[r] += p;
    }
  }
#pragma unroll
  for (int r = 0; r < 4; r++)
#pragma unroll
    for (int d = 1; d < 16; d <<= 1) sum[r] += __shfl_xor(sum[r], d, 64);

  // write P (bf16) to LDS [q][kv], same swizzle family
#pragma unroll
  for (int nt = 0; nt < 8; nt++) {
    int j = nt * 16 + lm;
#pragma unroll
    for (int r = 0; r < 4; r++) {
      int q = w * 16 + lg * 4 + r;
      int byte = (q * 256 + j * 2) ^ ((q & 7) << 4);
      *reinterpret_cast<unsigned short*>((char*)ps + byte) = f2bf(sf[nt][r]);
    }
  }
  __syncthreads();

  // ---- O = P V : A = P rows (q), B = vts rows (d) ----
  bf16x8 pa[4];
#pragma unroll
  for (int ks = 0; ks < 4; ks++) {
    int q = w * 16 + lm;
    int byte = (q * 256 + (ks * 32 + lg * 8) * 2) ^ ((q & 7) << 4);
    pa[ks] = *reinterpret_cast<const bf16x8*>((char*)ps + byte);
  }
  float rcpl[4];
#pragma unroll
  for (int r = 0; r < 4; r++) rcpl[r] = 1.0f / sum[r];
#pragma unroll
  for (int nt = 0; nt < 4; nt++) {
    f32x4 o = {};
#pragma unroll
    for (int ks = 0; ks < 4; ks++) {
      int dn = nt * 16 + lm;
      int byte = (dn * 256 + (ks * 32 + lg * 8) * 2) ^ ((dn & 7) << 4);
      bf16x8 vb = *reinterpret_cast<const bf16x8*>((char*)vts + byte);
      o = __builtin_amdgcn_mfma_f32_16x16x32_bf16(pa[ks], vb, o, 0, 0, 0);
    }
#pragma unroll
    for (int r = 0; r < 4; r++) {
      int sq = c * 64 + w * 16 + lg * 4 + r;
      int d = nt * 16 + lm;
      out[(size_t)(b * NS + sq) * (NH * ND) + h * ND + d] = o[r] * rcpl[r];
    }
  }
}

// ---------------- launch ----------------
extern "C" void kernel_launch(void* const* d_in, const int* in_sizes, int n_in,
                              void* d_out, int out_size, void* d_ws, size_t ws_size,
                              hipStream_t stream) {
  const float* hs = (const float*)d_in[0];
  const float* wq = (const float*)d_in[1];
  const float* wk = (const float*)d_in[2];
  const float* wv = (const float*)d_in[3];
  float* out = (float*)d_out;
  char* ws = (char*)d_ws;

  const size_t XB_BYTES = (size_t)NB * NS * NHID * 2;       // 64MB
  const size_t WT_BYTES = (size_t)3 * NHID * NHID * 2;      // 6MB
  const size_t QKV_BYTES = (size_t)NB * NH * NS * ND * 2;   // 64MB each
  unsigned short* xb = (unsigned short*)ws;
  unsigned short* wt = (unsigned short*)(ws + XB_BYTES);
  unsigned short* qg = (unsigned short*)(ws + XB_BYTES + WT_BYTES);
  unsigned short* kg = (unsigned short*)(ws + XB_BYTES + WT_BYTES + QKV_BYTES);
  unsigned short* vg = (unsigned short*)(ws + XB_BYTES + WT_BYTES + 2 * QKV_BYTES);

  hipLaunchKernelGGL(convert_x, dim3((NB * NS * NHID) / (256 * 8)), dim3(256), 0,
                     stream, hs, xb);
  hipLaunchKernelGGL(transpose_w, dim3(32, 32, 3), dim3(32, 8), 0, stream, wq, wk,
                     wv, wt);
  hipLaunchKernelGGL(gemm_qkv, dim3(3 * NHID / 128, (NB * NS) / 128), dim3(256), 0,
                     stream, xb, wt, qg, kg, vg);
  hipLaunchKernelGGL(attn_local, dim3(NCHUNK, NH, NB), dim3(256), 0, stream, qg, kg,
                     vg, out);
}